// Round 8
// baseline (420.661 us; speedup 1.0000x reference)
//
#include <hip/hip_runtime.h>
#include <math.h>
#include <stdint.h>

#define NEG_SENT -1e30f

__device__ __forceinline__ unsigned short f2bf(float f) {
    unsigned u = __float_as_uint(f);
    unsigned r = u + 0x7FFFu + ((u >> 16) & 1u);   // round-to-nearest-even
    return (unsigned short)(r >> 16);
}
__device__ __forceinline__ float bf2f(unsigned short h) {
    return __uint_as_float(((unsigned)h) << 16);
}

// ---------- fp32 register-blocked GEMM: 128x128 tile, 8x8/thread ----------
// C[M,N] = A[M,K] @ B[K,N].  Requires K % 16 == 0, N % 4 == 0.
// As stored [k][m] -> a-reads are wave broadcasts (free).
// Bs reads at 4*tx and 64+4*tx -> 2-way bank aliasing (free).
__global__ __launch_bounds__(256) void gemm_f32_xl(const float* __restrict__ A,
        const float* __restrict__ B, float* __restrict__ C,
        int M, int N, int K) {
    __shared__ float As[16][129];   // [k][m], padded
    __shared__ float Bs[16][132];   // [k][n], padded
    int tid = threadIdx.x;
    int tx = tid & 15;        // n-group
    int ty = tid >> 4;        // m-group
    int row0 = blockIdx.y * 128;
    int col0 = blockIdx.x * 128;
    float acc[8][8] = {};
    for (int k0 = 0; k0 < K; k0 += 16) {
        // stage A tile (128 rows x 16 k) as [k][m]
        #pragma unroll
        for (int i = 0; i < 2; ++i) {
            int idx = tid + i * 256;
            int m = idx >> 2;
            int k4 = (idx & 3) * 4;
            int gr = row0 + m;
            float4 v = make_float4(0.f, 0.f, 0.f, 0.f);
            if (gr < M) v = *(const float4*)&A[(long)gr * K + k0 + k4];
            As[k4 + 0][m] = v.x;
            As[k4 + 1][m] = v.y;
            As[k4 + 2][m] = v.z;
            As[k4 + 3][m] = v.w;
        }
        // stage B tile (16 k x 128 n)
        #pragma unroll
        for (int i = 0; i < 2; ++i) {
            int idx = tid + i * 256;
            int k = idx >> 5;
            int n4 = (idx & 31) * 4;
            int gc = col0 + n4;
            float4 v = make_float4(0.f, 0.f, 0.f, 0.f);
            if (gc + 3 < N) {
                v = *(const float4*)&B[(long)(k0 + k) * N + gc];
            } else {
                if (gc + 0 < N) v.x = B[(long)(k0 + k) * N + gc + 0];
                if (gc + 1 < N) v.y = B[(long)(k0 + k) * N + gc + 1];
                if (gc + 2 < N) v.z = B[(long)(k0 + k) * N + gc + 2];
                if (gc + 3 < N) v.w = B[(long)(k0 + k) * N + gc + 3];
            }
            *(float4*)&Bs[k][n4] = v;
        }
        __syncthreads();
        #pragma unroll
        for (int k = 0; k < 16; ++k) {
            float4 a0 = *(const float4*)&As[k][ty * 8];
            float4 a1 = *(const float4*)&As[k][ty * 8 + 4];
            float4 b0 = *(const float4*)&Bs[k][tx * 4];
            float4 b1 = *(const float4*)&Bs[k][64 + tx * 4];
            float am[8] = {a0.x, a0.y, a0.z, a0.w, a1.x, a1.y, a1.z, a1.w};
            float bn[8] = {b0.x, b0.y, b0.z, b0.w, b1.x, b1.y, b1.z, b1.w};
            #pragma unroll
            for (int i = 0; i < 8; ++i)
                #pragma unroll
                for (int j = 0; j < 8; ++j)
                    acc[i][j] += am[i] * bn[j];
        }
        __syncthreads();
    }
    #pragma unroll
    for (int i = 0; i < 8; ++i) {
        int gr = row0 + ty * 8 + i;
        if (gr >= M) continue;
        int gc0 = col0 + tx * 4;
        int gc1 = col0 + 64 + tx * 4;
        if (gc0 + 3 < N)
            *(float4*)&C[(long)gr * N + gc0] =
                make_float4(acc[i][0], acc[i][1], acc[i][2], acc[i][3]);
        if (gc1 + 3 < N)
            *(float4*)&C[(long)gr * N + gc1] =
                make_float4(acc[i][4], acc[i][5], acc[i][6], acc[i][7]);
    }
}

// ---------- generic fp32 tiled GEMM (kept for layer 2) ----------
template<int BM, int BN, int BK>
__global__ __launch_bounds__(256) void gemm_f32(const float* __restrict__ A,
        const float* __restrict__ B, float* __restrict__ C,
        int M, int N, int K) {
    __shared__ float As[BK][BM + 1];
    __shared__ float Bs[BK][BN + 1];
    int tid = threadIdx.x;
    int tx = tid & 15;
    int ty = tid >> 4;
    int row0 = blockIdx.y * BM;
    int col0 = blockIdx.x * BN;
    float acc[4][4] = {};
    for (int k0 = 0; k0 < K; k0 += BK) {
        #pragma unroll
        for (int i = 0; i < (BM * BK) / 256; ++i) {
            int idx = tid + i * 256;
            int r = idx / BK, c = idx % BK;
            int gr = row0 + r;
            float v = 0.f;
            if (gr < M) v = A[(long)gr * K + k0 + c];
            As[c][r] = v;
        }
        #pragma unroll
        for (int i = 0; i < (BK * BN) / 256; ++i) {
            int idx = tid + i * 256;
            int r = idx / BN, c = idx % BN;
            int gc = col0 + c;
            float v = 0.f;
            if (gc < N) v = B[(long)(k0 + r) * N + gc];
            Bs[r][c] = v;
        }
        __syncthreads();
        #pragma unroll
        for (int k = 0; k < BK; ++k) {
            float a[4], b[4];
            #pragma unroll
            for (int i = 0; i < 4; ++i) a[i] = As[k][ty * 4 + i];
            #pragma unroll
            for (int j = 0; j < 4; ++j) b[j] = Bs[k][tx * 4 + j];
            #pragma unroll
            for (int i = 0; i < 4; ++i)
                #pragma unroll
                for (int j = 0; j < 4; ++j)
                    acc[i][j] += a[i] * b[j];
        }
        __syncthreads();
    }
    #pragma unroll
    for (int i = 0; i < 4; ++i) {
        int gr = row0 + ty * 4 + i;
        if (gr >= M) continue;
        #pragma unroll
        for (int j = 0; j < 4; ++j) {
            int gc = col0 + tx * 4 + j;
            if (gc < N) C[(long)gr * N + gc] = acc[i][j];
        }
    }
}

// ---------- attention projections ----------
__global__ __launch_bounds__(256) void att_proj_h4(const float* __restrict__ xp,
        const float* __restrict__ att_s, const float* __restrict__ att_d,
        float* __restrict__ a_s, float* __restrict__ a_d,
        unsigned short* __restrict__ xph, int N) {
    int n = blockIdx.x;
    int t = threadIdx.x;
    float p = xp[(long)n * 256 + t];
    if (xph) xph[(long)n * 256 + t] = f2bf(p);
    float vs = p * att_s[t];
    float vd = p * att_d[t];
    #pragma unroll
    for (int off = 32; off; off >>= 1) {
        vs += __shfl_down(vs, off);
        vd += __shfl_down(vd, off);
    }
    if ((t & 63) == 0) {
        int h = t >> 6;
        a_s[n * 4 + h] = vs;
        a_d[n * 4 + h] = vd;
    }
}

__global__ __launch_bounds__(256) void att_proj_h1(const float* __restrict__ xp,
        const float* __restrict__ att_s, const float* __restrict__ att_d,
        float* __restrict__ a_s, float* __restrict__ a_d, int N) {
    int t = threadIdx.x;
    int n = blockIdx.x * 8 + (t >> 5);
    if (n >= N) return;
    int c = t & 31;
    float p = xp[(long)n * 32 + c];
    float vs = p * att_s[c];
    float vd = p * att_d[c];
    #pragma unroll
    for (int off = 16; off; off >>= 1) {
        vs += __shfl_xor(vs, off, 32);
        vd += __shfl_xor(vd, off, 32);
    }
    if (c == 0) { a_s[n] = vs; a_d[n] = vd; }
}

// ---------- CSR build ----------
__global__ __launch_bounds__(256) void count_deg(const int* __restrict__ ei,
        int E, int Etot, int* __restrict__ deg) {
    int e = blockIdx.x * 256 + threadIdx.x;
    if (e >= Etot) return;
    int d = (e < E) ? ei[E + e] : e - E;
    atomicAdd(&deg[d], 1);
}

__global__ __launch_bounds__(256) void scan_local(const int* __restrict__ deg,
        int* __restrict__ rowptr, int* __restrict__ blocksum, int N) {
    __shared__ int part[256];
    int b = blockIdx.x, t = threadIdx.x;
    int base = b * 1024 + t * 4;
    int4 v = make_int4(0, 0, 0, 0);
    if (base + 3 < N) {
        v = *(const int4*)(deg + base);
    } else {
        if (base + 0 < N) v.x = deg[base + 0];
        if (base + 1 < N) v.y = deg[base + 1];
        if (base + 2 < N) v.z = deg[base + 2];
        if (base + 3 < N) v.w = deg[base + 3];
    }
    part[t] = v.x + v.y + v.z + v.w;
    __syncthreads();
    #pragma unroll
    for (int off = 1; off < 256; off <<= 1) {
        int val = (t >= off) ? part[t - off] : 0;
        __syncthreads();
        part[t] += val;
        __syncthreads();
    }
    if (t == 255) blocksum[b] = part[255];
    int r0 = (t > 0) ? part[t - 1] : 0;
    int r1 = r0 + v.x;
    int r2 = r1 + v.y;
    int r3 = r2 + v.z;
    if (base + 3 < N) {
        *(int4*)(rowptr + base) = make_int4(r0, r1, r2, r3);
    } else {
        if (base + 0 < N) rowptr[base + 0] = r0;
        if (base + 1 < N) rowptr[base + 1] = r1;
        if (base + 2 < N) rowptr[base + 2] = r2;
        if (base + 3 < N) rowptr[base + 3] = r3;
    }
}

__global__ __launch_bounds__(256) void scan_block_sums(const int* __restrict__ blocksum,
        int* __restrict__ blockoff, int nb) {
    __shared__ int part[256];
    int t = threadIdx.x;
    part[t] = (t < nb) ? blocksum[t] : 0;
    __syncthreads();
    #pragma unroll
    for (int off = 1; off < 256; off <<= 1) {
        int val = (t >= off) ? part[t - off] : 0;
        __syncthreads();
        part[t] += val;
        __syncthreads();
    }
    if (t < nb) blockoff[t] = (t > 0) ? part[t - 1] : 0;
}

__global__ __launch_bounds__(256) void scan_add(int* __restrict__ rowptr,
        const int* __restrict__ blockoff, int* __restrict__ cursor,
        int N, int Etot) {
    int b = blockIdx.x, t = threadIdx.x;
    int base = b * 1024 + t * 4;
    int off = blockoff[b];
    if (base + 3 < N) {
        int4 v = *(const int4*)(rowptr + base);
        v.x += off; v.y += off; v.z += off; v.w += off;
        *(int4*)(rowptr + base) = v;
        *(int4*)(cursor + base) = v;
    } else {
        for (int i = 0; i < 4; ++i) {
            if (base + i < N) {
                int v = rowptr[base + i] + off;
                rowptr[base + i] = v;
                cursor[base + i] = v;
            }
        }
    }
    if (b == 0 && t == 0) rowptr[N] = Etot;
}

__global__ __launch_bounds__(256) void scatter_edges(const int* __restrict__ ei,
        int E, int Etot, int* __restrict__ cursor, int* __restrict__ csr_src) {
    int e = blockIdx.x * 256 + threadIdx.x;
    if (e >= Etot) return;
    int s, d;
    if (e < E) { s = ei[e]; d = ei[E + e]; } else { s = e - E; d = s; }
    int pos = atomicAdd(&cursor[d], 1);
    csr_src[pos] = s;
}

// ---------- canonicalize CSR rows (determinism across calls/replays) ----------
__global__ __launch_bounds__(256) void sort_rows(const int* __restrict__ rowptr,
        int* __restrict__ csr_src, int N) {
    __shared__ int buf[4][256];
    __shared__ int mxw[4];
    int t = threadIdx.x;
    int w = t >> 6;
    int lane = t & 63;
    int d = blockIdx.x * 4 + w;
    int row0 = 0, deg = 0;
    if (d < N) { row0 = rowptr[d]; deg = rowptr[d + 1] - row0; }
    int capped = (deg <= 256) ? deg : 0;   // huge rows: fallback below
    for (int j = lane; j < capped; j += 64) buf[w][j] = csr_src[row0 + j];
    int m = capped;
    #pragma unroll
    for (int off = 32; off; off >>= 1) m = max(m, __shfl_xor(m, off));
    if (lane == 0) mxw[w] = m;
    __syncthreads();
    int itmax = max(max(mxw[0], mxw[1]), max(mxw[2], mxw[3]));
    for (int it = 0; it < itmax; ++it) {
        int start = it & 1;
        #pragma unroll
        for (int rep = 0; rep < 2; ++rep) {
            int k = start + 2 * lane + rep * 128;
            if (k + 1 < capped) {
                int a = buf[w][k], b = buf[w][k + 1];
                if (a > b) { buf[w][k] = b; buf[w][k + 1] = a; }
            }
        }
        __syncthreads();
    }
    for (int j = lane; j < capped; j += 64) csr_src[row0 + j] = buf[w][j];
    if (deg > 256 && lane == 0) {
        for (int i = 1; i < deg; ++i) {
            int key = csr_src[row0 + i];
            int k = i - 1;
            while (k >= 0 && csr_src[row0 + k] > key) {
                csr_src[row0 + k + 1] = csr_src[row0 + k];
                --k;
            }
            csr_src[row0 + k + 1] = key;
        }
    }
}

// ---------- softmax stats + coefficient precompute ----------
__device__ __forceinline__ void merge_ms(float& m, float& s, float m2, float s2) {
    float mn = fmaxf(m, m2);
    s = s * expf(m - mn) + s2 * expf(m2 - mn);
    m = mn;
}

__global__ __launch_bounds__(256) void stats_coeff_h4(const int* __restrict__ rowptr,
        const int* __restrict__ csr_src, const float* __restrict__ a_s,
        const float* __restrict__ a_d, float* __restrict__ coeff, int N) {
    int t = threadIdx.x;
    int d = blockIdx.x * 4 + (t >> 6);
    if (d >= N) return;
    int lane = t & 63;
    int h = lane & 3;
    int j0 = lane >> 2;
    int row0 = rowptr[d];
    int deg = rowptr[d + 1] - row0;
    float ad = a_d[d * 4 + h];
    float m = NEG_SENT, s = 0.f;
    for (int j = j0; j < deg; j += 16) {
        int sn = csr_src[row0 + j];
        float l = a_s[sn * 4 + h] + ad;
        l = l > 0.f ? l : 0.2f * l;
        float mn = fmaxf(m, l);
        s = s * expf(m - mn) + expf(l - mn);
        m = mn;
    }
    #pragma unroll
    for (int off = 4; off <= 32; off <<= 1) {
        float m2 = __shfl_xor(m, off);
        float s2 = __shfl_xor(s, off);
        merge_ms(m, s, m2, s2);
    }
    float inv = 1.f / (s + 1e-16f);
    for (int j = j0; j < deg; j += 16) {
        int sn = csr_src[row0 + j];
        float l = a_s[sn * 4 + h] + ad;
        l = l > 0.f ? l : 0.2f * l;
        coeff[(long)(row0 + j) * 4 + h] = expf(l - m) * inv;
    }
}

__global__ __launch_bounds__(256) void stats_coeff_h1(const int* __restrict__ rowptr,
        const int* __restrict__ csr_src, const float* __restrict__ a_s,
        const float* __restrict__ a_d, float* __restrict__ coeff, int N) {
    int t = threadIdx.x;
    int d = blockIdx.x * 4 + (t >> 6);
    if (d >= N) return;
    int lane = t & 63;
    int row0 = rowptr[d];
    int deg = rowptr[d + 1] - row0;
    float ad = a_d[d];
    float m = NEG_SENT, s = 0.f;
    for (int j = lane; j < deg; j += 64) {
        int sn = csr_src[row0 + j];
        float l = a_s[sn] + ad;
        l = l > 0.f ? l : 0.2f * l;
        float mn = fmaxf(m, l);
        s = s * expf(m - mn) + expf(l - mn);
        m = mn;
    }
    #pragma unroll
    for (int off = 1; off <= 32; off <<= 1) {
        float m2 = __shfl_xor(m, off);
        float s2 = __shfl_xor(s, off);
        merge_ms(m, s, m2, s2);
    }
    float inv = 1.f / (s + 1e-16f);
    for (int j = lane; j < deg; j += 64) {
        int sn = csr_src[row0 + j];
        float l = a_s[sn] + ad;
        l = l > 0.f ? l : 0.2f * l;
        coeff[row0 + j] = expf(l - m) * inv;
    }
}

// ---------- gather aggregation ----------
__global__ __launch_bounds__(256) void agg1_gather_bf16(const int* __restrict__ rowptr,
        const int* __restrict__ csr_src, const float* __restrict__ coeff,
        const ushort4* __restrict__ xph4, const float* __restrict__ bias,
        float4* __restrict__ hout4, int N) {
    int t = threadIdx.x;
    int d = blockIdx.x * 4 + (t >> 6);
    if (d >= N) return;
    int lane = t & 63;
    int hsel = lane >> 4;
    int row0 = rowptr[d];
    int deg = rowptr[d + 1] - row0;
    float4 acc = make_float4(0.f, 0.f, 0.f, 0.f);
    int j = 0;
    for (; j + 4 <= deg; j += 4) {
        long e0 = row0 + j;
        int s0 = csr_src[e0 + 0];
        int s1 = csr_src[e0 + 1];
        int s2 = csr_src[e0 + 2];
        int s3 = csr_src[e0 + 3];
        float c0 = coeff[(e0 + 0) * 4 + hsel];
        float c1 = coeff[(e0 + 1) * 4 + hsel];
        float c2 = coeff[(e0 + 2) * 4 + hsel];
        float c3 = coeff[(e0 + 3) * 4 + hsel];
        ushort4 u0 = xph4[(long)s0 * 64 + lane];
        ushort4 u1 = xph4[(long)s1 * 64 + lane];
        ushort4 u2 = xph4[(long)s2 * 64 + lane];
        ushort4 u3 = xph4[(long)s3 * 64 + lane];
        acc.x += c0 * bf2f(u0.x); acc.y += c0 * bf2f(u0.y);
        acc.z += c0 * bf2f(u0.z); acc.w += c0 * bf2f(u0.w);
        acc.x += c1 * bf2f(u1.x); acc.y += c1 * bf2f(u1.y);
        acc.z += c1 * bf2f(u1.z); acc.w += c1 * bf2f(u1.w);
        acc.x += c2 * bf2f(u2.x); acc.y += c2 * bf2f(u2.y);
        acc.z += c2 * bf2f(u2.z); acc.w += c2 * bf2f(u2.w);
        acc.x += c3 * bf2f(u3.x); acc.y += c3 * bf2f(u3.y);
        acc.z += c3 * bf2f(u3.z); acc.w += c3 * bf2f(u3.w);
    }
    for (; j < deg; ++j) {
        long e = row0 + j;
        int s = csr_src[e];
        float c = coeff[e * 4 + hsel];
        ushort4 u = xph4[(long)s * 64 + lane];
        acc.x += c * bf2f(u.x); acc.y += c * bf2f(u.y);
        acc.z += c * bf2f(u.z); acc.w += c * bf2f(u.w);
    }
    float4 b = ((const float4*)bias)[lane];
    float4 o;
    float vx = acc.x + b.x; o.x = vx > 0.f ? vx : expm1f(vx);
    float vy = acc.y + b.y; o.y = vy > 0.f ? vy : expm1f(vy);
    float vz = acc.z + b.z; o.z = vz > 0.f ? vz : expm1f(vz);
    float vw = acc.w + b.w; o.w = vw > 0.f ? vw : expm1f(vw);
    hout4[(long)d * 64 + lane] = o;
}

// fp32 fallback (only if ws too small for bf16 copy)
__global__ __launch_bounds__(256) void agg1_gather(const int* __restrict__ rowptr,
        const int* __restrict__ csr_src, const float* __restrict__ coeff,
        const float4* __restrict__ xp4, const float* __restrict__ bias,
        float4* __restrict__ hout4, int N) {
    int t = threadIdx.x;
    int d = blockIdx.x * 4 + (t >> 6);
    if (d >= N) return;
    int lane = t & 63;
    int hsel = lane >> 4;
    int row0 = rowptr[d];
    int deg = rowptr[d + 1] - row0;
    float4 acc = make_float4(0.f, 0.f, 0.f, 0.f);
    for (int j = 0; j < deg; ++j) {
        long e = row0 + j;
        int s = csr_src[e];
        float c = coeff[e * 4 + hsel];
        float4 v = xp4[(long)s * 64 + lane];
        acc.x += c * v.x; acc.y += c * v.y;
        acc.z += c * v.z; acc.w += c * v.w;
    }
    float4 b = ((const float4*)bias)[lane];
    float4 o;
    float vx = acc.x + b.x; o.x = vx > 0.f ? vx : expm1f(vx);
    float vy = acc.y + b.y; o.y = vy > 0.f ? vy : expm1f(vy);
    float vz = acc.z + b.z; o.z = vz > 0.f ? vz : expm1f(vz);
    float vw = acc.w + b.w; o.w = vw > 0.f ? vw : expm1f(vw);
    hout4[(long)d * 64 + lane] = o;
}

// layer 2: 8 nodes/block, 32 lanes per node; fused bias + row softmax; 4x MLP
__global__ __launch_bounds__(256) void agg2_softmax(const int* __restrict__ rowptr,
        const int* __restrict__ csr_src, const float* __restrict__ coeff,
        const float* __restrict__ xp, const float* __restrict__ bias,
        float* __restrict__ out, int N) {
    int t = threadIdx.x;
    int d = blockIdx.x * 8 + (t >> 5);
    if (d >= N) return;
    int c = t & 31;
    int row0 = rowptr[d];
    int deg = rowptr[d + 1] - row0;
    float acc = 0.f;
    int j = 0;
    for (; j + 4 <= deg; j += 4) {
        long e0 = row0 + j;
        int s0 = csr_src[e0 + 0];
        int s1 = csr_src[e0 + 1];
        int s2 = csr_src[e0 + 2];
        int s3 = csr_src[e0 + 3];
        float c0 = coeff[e0 + 0];
        float c1 = coeff[e0 + 1];
        float c2 = coeff[e0 + 2];
        float c3 = coeff[e0 + 3];
        float v0 = xp[(long)s0 * 32 + c];
        float v1 = xp[(long)s1 * 32 + c];
        float v2 = xp[(long)s2 * 32 + c];
        float v3 = xp[(long)s3 * 32 + c];
        acc += c0 * v0;
        acc += c1 * v1;
        acc += c2 * v2;
        acc += c3 * v3;
    }
    for (; j < deg; ++j) {
        long e = row0 + j;
        int s = csr_src[e];
        acc += coeff[e] * xp[(long)s * 32 + c];
    }
    float v = acc + bias[c];
    float mx = v;
    #pragma unroll
    for (int off = 16; off; off >>= 1) mx = fmaxf(mx, __shfl_xor(mx, off, 32));
    float ex = expf(v - mx);
    float sm = ex;
    #pragma unroll
    for (int off = 16; off; off >>= 1) sm += __shfl_xor(sm, off, 32);
    out[(long)d * 32 + c] = ex / sm;
}

// ---------- host ----------
extern "C" void kernel_launch(void* const* d_in, const int* in_sizes, int n_in,
                              void* d_out, int out_size, void* d_ws, size_t ws_size,
                              hipStream_t stream) {
    const float* x   = (const float*)d_in[0];
    const int*   ei  = (const int*)d_in[1];
    const float* W1  = (const float*)d_in[2];
    const float* as1 = (const float*)d_in[3];
    const float* ad1 = (const float*)d_in[4];
    const float* b1  = (const float*)d_in[5];
    const float* W2  = (const float*)d_in[6];
    const float* as2 = (const float*)d_in[7];
    const float* ad2 = (const float*)d_in[8];
    const float* b2  = (const float*)d_in[9];
    float* out = (float*)d_out;

    const int N = in_sizes[0] / 128;     // 50000
    const int E = in_sizes[1] / 2;       // 640000
    const int Etot = E + N;              // + self loops

    // workspace layout (16B-aligned blocks)
    float* ws = (float*)d_ws;
    float* xp1    = ws;                        // N*256 (reused as xp2)
    float* h      = xp1 + (long)N * 256;       // N*256 (reused as coeff2)
    float* a_s1   = h + (long)N * 256;         // N*4
    float* a_d1   = a_s1 + N * 4;              // N*4
    float* a_s2   = a_d1 + N * 4;              // N
    float* a_d2   = a_s2 + N;                  // N
    float* coeff1 = a_d2 + N;                  // Etot*4
    int* deg      = (int*)(coeff1 + (long)Etot * 4); // N
    int* rowptr   = deg + N;                   // N+4 (padded)
    int* cursor   = rowptr + N + 4;            // N
    int* csr_src  = cursor + N;                // Etot
    int* blocksum = csr_src + Etot;            // 256
    int* blockoff = blocksum + 256;            // 256
    unsigned short* xp1h = (unsigned short*)
        ((((uintptr_t)(blockoff + 256)) + 15) & ~(uintptr_t)15);  // N*256 bf16
    size_t need = (size_t)((char*)(xp1h + (size_t)N * 256) - (char*)d_ws);
    bool use_bf16 = (ws_size >= need);
    float* xp2    = xp1;                       // xp1 dead after layer-1 agg
    float* coeff2 = h;                         // h dead after gemm2

    hipMemsetAsync(deg, 0, (size_t)N * sizeof(int), stream);

    // ---- CSR build (shared by both layers) ----
    int nbE = (Etot + 255) / 256;
    int nbS = (N + 1023) / 1024;
    count_deg<<<nbE, 256, 0, stream>>>(ei, E, Etot, deg);
    scan_local<<<nbS, 256, 0, stream>>>(deg, rowptr, blocksum, N);
    scan_block_sums<<<1, 256, 0, stream>>>(blocksum, blockoff, nbS);
    scan_add<<<nbS, 256, 0, stream>>>(rowptr, blockoff, cursor, N, Etot);
    scatter_edges<<<nbE, 256, 0, stream>>>(ei, E, Etot, cursor, csr_src);
    sort_rows<<<(N + 3) / 4, 256, 0, stream>>>(rowptr, csr_src, N);

    // ---- layer 1 ----
    {
        dim3 g((256 + 127) / 128, (N + 127) / 128);
        gemm_f32_xl<<<g, 256, 0, stream>>>(x, W1, xp1, N, 256, 128);
    }
    att_proj_h4<<<N, 256, 0, stream>>>(xp1, as1, ad1, a_s1, a_d1,
                                       use_bf16 ? xp1h : nullptr, N);
    stats_coeff_h4<<<(N + 3) / 4, 256, 0, stream>>>(rowptr, csr_src, a_s1, a_d1,
                                                    coeff1, N);
    if (use_bf16) {
        agg1_gather_bf16<<<(N + 3) / 4, 256, 0, stream>>>(rowptr, csr_src, coeff1,
                                                  (const ushort4*)xp1h, b1,
                                                  (float4*)h, N);
    } else {
        agg1_gather<<<(N + 3) / 4, 256, 0, stream>>>(rowptr, csr_src, coeff1,
                                                  (const float4*)xp1, b1,
                                                  (float4*)h, N);
    }

    // ---- layer 2 ----
    {
        dim3 g(1, (N + 63) / 64);
        gemm_f32<64, 64, 16><<<g, 256, 0, stream>>>(h, W2, xp2, N, 32, 256);
    }
    att_proj_h1<<<(N + 7) / 8, 256, 0, stream>>>(xp2, as2, ad2, a_s2, a_d2, N);
    stats_coeff_h1<<<(N + 3) / 4, 256, 0, stream>>>(rowptr, csr_src, a_s2, a_d2,
                                                    coeff2, N);
    agg2_softmax<<<(N + 7) / 8, 256, 0, stream>>>(rowptr, csr_src, coeff2,
                                                  xp2, b2, out, N);
}

// Round 9
// 380.581 us; speedup vs baseline: 1.1053x; 1.1053x over previous
//
#include <hip/hip_runtime.h>
#include <math.h>
#include <stdint.h>

#define NEG_SENT -1e30f

typedef __attribute__((ext_vector_type(8))) short bf16x8;
typedef __attribute__((ext_vector_type(4))) float f32x4;

__device__ __forceinline__ unsigned short f2bf(float f) {
    unsigned u = __float_as_uint(f);
    unsigned r = u + 0x7FFFu + ((u >> 16) & 1u);   // round-to-nearest-even
    return (unsigned short)(r >> 16);
}
__device__ __forceinline__ float bf2f(unsigned short h) {
    return __uint_as_float(((unsigned)h) << 16);
}

// ---------- prep: fp32 -> bf16 cast (vectorized) ----------
__global__ __launch_bounds__(256) void cast_bf16(const float* __restrict__ in,
        unsigned short* __restrict__ out, long n) {
    long i = ((long)blockIdx.x * 256 + threadIdx.x) * 4;
    if (i + 3 < n) {
        float4 v = *(const float4*)&in[i];
        ushort4 o;
        o.x = f2bf(v.x); o.y = f2bf(v.y); o.z = f2bf(v.z); o.w = f2bf(v.w);
        *(ushort4*)&out[i] = o;
    } else {
        for (long k = i; k < n; ++k) out[k] = f2bf(in[k]);
    }
}

// ---------- prep: W1 [128][256] f32 -> W1t [256][128] bf16 ----------
__global__ __launch_bounds__(256) void transpose_w1(const float* __restrict__ w,
        unsigned short* __restrict__ wt) {
    int idx = blockIdx.x * 256 + threadIdx.x;   // 32768 total
    int k = idx & 127;
    int n = idx >> 7;
    wt[idx] = f2bf(w[k * 256 + n]);             // wt[n][k]
}

// ---------- layer-1 GEMM via bf16 MFMA ----------
// xp[M,256] = xb[M,128] @ W1 (w1t is W1^T as [256][128] bf16).
// One wave per 16 output rows; 16 col-tiles x 4 k-steps of 16x16x32 MFMA.
// A frag: lane l elem j = A[row0 + (l&15)][(l>>4)*8 + j + 32*k0]  (bf16x8, 16B)
// B frag: lane l elem j = B[k][col0 + (l&15)] = w1t[col0+(l&15)][same k range]
// C/D:    col = lane&15, row = (lane>>4)*4 + reg   [m89-verified]
__global__ __launch_bounds__(256) void gemm1_mfma(
        const unsigned short* __restrict__ xb,
        const unsigned short* __restrict__ w1t,
        float* __restrict__ xp, int M) {
    int wave = (int)(((long)blockIdx.x * 256 + threadIdx.x) >> 6);
    int lane = threadIdx.x & 63;
    int row0 = wave * 16;
    if (row0 >= M) return;
    int r = lane & 15;
    int g = lane >> 4;
    bf16x8 a[4];
    const unsigned short* arow = xb + (long)(row0 + r) * 128 + g * 8;
    #pragma unroll
    for (int k0 = 0; k0 < 4; ++k0)
        a[k0] = *(const bf16x8*)(arow + k0 * 32);
    f32x4 acc[16];
    #pragma unroll
    for (int nt = 0; nt < 16; ++nt) acc[nt] = (f32x4){0.f, 0.f, 0.f, 0.f};
    #pragma unroll
    for (int nt = 0; nt < 16; ++nt) {
        const unsigned short* brow = w1t + (long)(nt * 16 + r) * 128 + g * 8;
        #pragma unroll
        for (int k0 = 0; k0 < 4; ++k0) {
            bf16x8 b = *(const bf16x8*)(brow + k0 * 32);
            acc[nt] = __builtin_amdgcn_mfma_f32_16x16x32_bf16(a[k0], b, acc[nt], 0, 0, 0);
        }
    }
    #pragma unroll
    for (int nt = 0; nt < 16; ++nt) {
        #pragma unroll
        for (int q = 0; q < 4; ++q) {
            xp[(long)(row0 + g * 4 + q) * 256 + nt * 16 + r] = acc[nt][q];
        }
    }
}

// ---------- generic fp32 tiled GEMM (layer 2) ----------
template<int BM, int BN, int BK>
__global__ __launch_bounds__(256) void gemm_f32(const float* __restrict__ A,
        const float* __restrict__ B, float* __restrict__ C,
        int M, int N, int K) {
    __shared__ float As[BK][BM + 1];
    __shared__ float Bs[BK][BN + 1];
    int tid = threadIdx.x;
    int tx = tid & 15;
    int ty = tid >> 4;
    int row0 = blockIdx.y * BM;
    int col0 = blockIdx.x * BN;
    float acc[4][4] = {};
    for (int k0 = 0; k0 < K; k0 += BK) {
        #pragma unroll
        for (int i = 0; i < (BM * BK) / 256; ++i) {
            int idx = tid + i * 256;
            int r = idx / BK, c = idx % BK;
            int gr = row0 + r;
            float v = 0.f;
            if (gr < M) v = A[(long)gr * K + k0 + c];
            As[c][r] = v;
        }
        #pragma unroll
        for (int i = 0; i < (BK * BN) / 256; ++i) {
            int idx = tid + i * 256;
            int r = idx / BN, c = idx % BN;
            int gc = col0 + c;
            float v = 0.f;
            if (gc < N) v = B[(long)(k0 + r) * N + gc];
            Bs[r][c] = v;
        }
        __syncthreads();
        #pragma unroll
        for (int k = 0; k < BK; ++k) {
            float a[4], b[4];
            #pragma unroll
            for (int i = 0; i < 4; ++i) a[i] = As[k][ty * 4 + i];
            #pragma unroll
            for (int j = 0; j < 4; ++j) b[j] = Bs[k][tx * 4 + j];
            #pragma unroll
            for (int i = 0; i < 4; ++i)
                #pragma unroll
                for (int j = 0; j < 4; ++j)
                    acc[i][j] += a[i] * b[j];
        }
        __syncthreads();
    }
    #pragma unroll
    for (int i = 0; i < 4; ++i) {
        int gr = row0 + ty * 4 + i;
        if (gr >= M) continue;
        #pragma unroll
        for (int j = 0; j < 4; ++j) {
            int gc = col0 + tx * 4 + j;
            if (gc < N) C[(long)gr * N + gc] = acc[i][j];
        }
    }
}

// ---------- attention projections ----------
__global__ __launch_bounds__(256) void att_proj_h4(const float* __restrict__ xp,
        const float* __restrict__ att_s, const float* __restrict__ att_d,
        float* __restrict__ a_s, float* __restrict__ a_d,
        unsigned short* __restrict__ xph, int N) {
    int n = blockIdx.x;
    int t = threadIdx.x;
    float p = xp[(long)n * 256 + t];
    if (xph) xph[(long)n * 256 + t] = f2bf(p);
    float vs = p * att_s[t];
    float vd = p * att_d[t];
    #pragma unroll
    for (int off = 32; off; off >>= 1) {
        vs += __shfl_down(vs, off);
        vd += __shfl_down(vd, off);
    }
    if ((t & 63) == 0) {
        int h = t >> 6;
        a_s[n * 4 + h] = vs;
        a_d[n * 4 + h] = vd;
    }
}

__global__ __launch_bounds__(256) void att_proj_h1(const float* __restrict__ xp,
        const float* __restrict__ att_s, const float* __restrict__ att_d,
        float* __restrict__ a_s, float* __restrict__ a_d, int N) {
    int t = threadIdx.x;
    int n = blockIdx.x * 8 + (t >> 5);
    if (n >= N) return;
    int c = t & 31;
    float p = xp[(long)n * 32 + c];
    float vs = p * att_s[c];
    float vd = p * att_d[c];
    #pragma unroll
    for (int off = 16; off; off >>= 1) {
        vs += __shfl_xor(vs, off, 32);
        vd += __shfl_xor(vd, off, 32);
    }
    if (c == 0) { a_s[n] = vs; a_d[n] = vd; }
}

// ---------- CSR build ----------
__global__ __launch_bounds__(256) void count_deg(const int* __restrict__ ei,
        int E, int Etot, int* __restrict__ deg) {
    int e = blockIdx.x * 256 + threadIdx.x;
    if (e >= Etot) return;
    int d = (e < E) ? ei[E + e] : e - E;
    atomicAdd(&deg[d], 1);
}

__global__ __launch_bounds__(256) void scan_local(const int* __restrict__ deg,
        int* __restrict__ rowptr, int* __restrict__ blocksum, int N) {
    __shared__ int part[256];
    int b = blockIdx.x, t = threadIdx.x;
    int base = b * 1024 + t * 4;
    int4 v = make_int4(0, 0, 0, 0);
    if (base + 3 < N) {
        v = *(const int4*)(deg + base);
    } else {
        if (base + 0 < N) v.x = deg[base + 0];
        if (base + 1 < N) v.y = deg[base + 1];
        if (base + 2 < N) v.z = deg[base + 2];
        if (base + 3 < N) v.w = deg[base + 3];
    }
    part[t] = v.x + v.y + v.z + v.w;
    __syncthreads();
    #pragma unroll
    for (int off = 1; off < 256; off <<= 1) {
        int val = (t >= off) ? part[t - off] : 0;
        __syncthreads();
        part[t] += val;
        __syncthreads();
    }
    if (t == 255) blocksum[b] = part[255];
    int r0 = (t > 0) ? part[t - 1] : 0;
    int r1 = r0 + v.x;
    int r2 = r1 + v.y;
    int r3 = r2 + v.z;
    if (base + 3 < N) {
        *(int4*)(rowptr + base) = make_int4(r0, r1, r2, r3);
    } else {
        if (base + 0 < N) rowptr[base + 0] = r0;
        if (base + 1 < N) rowptr[base + 1] = r1;
        if (base + 2 < N) rowptr[base + 2] = r2;
        if (base + 3 < N) rowptr[base + 3] = r3;
    }
}

__global__ __launch_bounds__(256) void scan_block_sums(const int* __restrict__ blocksum,
        int* __restrict__ blockoff, int nb) {
    __shared__ int part[256];
    int t = threadIdx.x;
    part[t] = (t < nb) ? blocksum[t] : 0;
    __syncthreads();
    #pragma unroll
    for (int off = 1; off < 256; off <<= 1) {
        int val = (t >= off) ? part[t - off] : 0;
        __syncthreads();
        part[t] += val;
        __syncthreads();
    }
    if (t < nb) blockoff[t] = (t > 0) ? part[t - 1] : 0;
}

__global__ __launch_bounds__(256) void scan_add(int* __restrict__ rowptr,
        const int* __restrict__ blockoff, int* __restrict__ cursor,
        int N, int Etot) {
    int b = blockIdx.x, t = threadIdx.x;
    int base = b * 1024 + t * 4;
    int off = blockoff[b];
    if (base + 3 < N) {
        int4 v = *(const int4*)(rowptr + base);
        v.x += off; v.y += off; v.z += off; v.w += off;
        *(int4*)(rowptr + base) = v;
        *(int4*)(cursor + base) = v;
    } else {
        for (int i = 0; i < 4; ++i) {
            if (base + i < N) {
                int v = rowptr[base + i] + off;
                rowptr[base + i] = v;
                cursor[base + i] = v;
            }
        }
    }
    if (b == 0 && t == 0) rowptr[N] = Etot;
}

__global__ __launch_bounds__(256) void scatter_edges(const int* __restrict__ ei,
        int E, int Etot, int* __restrict__ cursor, int* __restrict__ csr_src) {
    int e = blockIdx.x * 256 + threadIdx.x;
    if (e >= Etot) return;
    int s, d;
    if (e < E) { s = ei[e]; d = ei[E + e]; } else { s = e - E; d = s; }
    int pos = atomicAdd(&cursor[d], 1);
    csr_src[pos] = s;
}

// ---------- canonicalize CSR rows (determinism across calls/replays) ----------
__global__ __launch_bounds__(256) void sort_rows(const int* __restrict__ rowptr,
        int* __restrict__ csr_src, int N) {
    __shared__ int buf[4][256];
    __shared__ int mxw[4];
    int t = threadIdx.x;
    int w = t >> 6;
    int lane = t & 63;
    int d = blockIdx.x * 4 + w;
    int row0 = 0, deg = 0;
    if (d < N) { row0 = rowptr[d]; deg = rowptr[d + 1] - row0; }
    int capped = (deg <= 256) ? deg : 0;   // huge rows: fallback below
    for (int j = lane; j < capped; j += 64) buf[w][j] = csr_src[row0 + j];
    int m = capped;
    #pragma unroll
    for (int off = 32; off; off >>= 1) m = max(m, __shfl_xor(m, off));
    if (lane == 0) mxw[w] = m;
    __syncthreads();
    int itmax = max(max(mxw[0], mxw[1]), max(mxw[2], mxw[3]));
    for (int it = 0; it < itmax; ++it) {
        int start = it & 1;
        #pragma unroll
        for (int rep = 0; rep < 2; ++rep) {
            int k = start + 2 * lane + rep * 128;
            if (k + 1 < capped) {
                int a = buf[w][k], b = buf[w][k + 1];
                if (a > b) { buf[w][k] = b; buf[w][k + 1] = a; }
            }
        }
        __syncthreads();
    }
    for (int j = lane; j < capped; j += 64) csr_src[row0 + j] = buf[w][j];
    if (deg > 256 && lane == 0) {
        for (int i = 1; i < deg; ++i) {
            int key = csr_src[row0 + i];
            int k = i - 1;
            while (k >= 0 && csr_src[row0 + k] > key) {
                csr_src[row0 + k + 1] = csr_src[row0 + k];
                --k;
            }
            csr_src[row0 + k + 1] = key;
        }
    }
}

// ---------- softmax stats + coefficient precompute ----------
__device__ __forceinline__ void merge_ms(float& m, float& s, float m2, float s2) {
    float mn = fmaxf(m, m2);
    s = s * expf(m - mn) + s2 * expf(m2 - mn);
    m = mn;
}

__global__ __launch_bounds__(256) void stats_coeff_h4(const int* __restrict__ rowptr,
        const int* __restrict__ csr_src, const float* __restrict__ a_s,
        const float* __restrict__ a_d, float* __restrict__ coeff, int N) {
    int t = threadIdx.x;
    int d = blockIdx.x * 4 + (t >> 6);
    if (d >= N) return;
    int lane = t & 63;
    int h = lane & 3;
    int j0 = lane >> 2;
    int row0 = rowptr[d];
    int deg = rowptr[d + 1] - row0;
    float ad = a_d[d * 4 + h];
    float m = NEG_SENT, s = 0.f;
    for (int j = j0; j < deg; j += 16) {
        int sn = csr_src[row0 + j];
        float l = a_s[sn * 4 + h] + ad;
        l = l > 0.f ? l : 0.2f * l;
        float mn = fmaxf(m, l);
        s = s * expf(m - mn) + expf(l - mn);
        m = mn;
    }
    #pragma unroll
    for (int off = 4; off <= 32; off <<= 1) {
        float m2 = __shfl_xor(m, off);
        float s2 = __shfl_xor(s, off);
        merge_ms(m, s, m2, s2);
    }
    float inv = 1.f / (s + 1e-16f);
    for (int j = j0; j < deg; j += 16) {
        int sn = csr_src[row0 + j];
        float l = a_s[sn * 4 + h] + ad;
        l = l > 0.f ? l : 0.2f * l;
        coeff[(long)(row0 + j) * 4 + h] = expf(l - m) * inv;
    }
}

__global__ __launch_bounds__(256) void stats_coeff_h1(const int* __restrict__ rowptr,
        const int* __restrict__ csr_src, const float* __restrict__ a_s,
        const float* __restrict__ a_d, float* __restrict__ coeff, int N) {
    int t = threadIdx.x;
    int d = blockIdx.x * 4 + (t >> 6);
    if (d >= N) return;
    int lane = t & 63;
    int row0 = rowptr[d];
    int deg = rowptr[d + 1] - row0;
    float ad = a_d[d];
    float m = NEG_SENT, s = 0.f;
    for (int j = lane; j < deg; j += 64) {
        int sn = csr_src[row0 + j];
        float l = a_s[sn] + ad;
        l = l > 0.f ? l : 0.2f * l;
        float mn = fmaxf(m, l);
        s = s * expf(m - mn) + expf(l - mn);
        m = mn;
    }
    #pragma unroll
    for (int off = 1; off <= 32; off <<= 1) {
        float m2 = __shfl_xor(m, off);
        float s2 = __shfl_xor(s, off);
        merge_ms(m, s, m2, s2);
    }
    float inv = 1.f / (s + 1e-16f);
    for (int j = lane; j < deg; j += 64) {
        int sn = csr_src[row0 + j];
        float l = a_s[sn] + ad;
        l = l > 0.f ? l : 0.2f * l;
        coeff[row0 + j] = expf(l - m) * inv;
    }
}

// ---------- gather aggregation ----------
__global__ __launch_bounds__(256) void agg1_gather_bf16(const int* __restrict__ rowptr,
        const int* __restrict__ csr_src, const float* __restrict__ coeff,
        const ushort4* __restrict__ xph4, const float* __restrict__ bias,
        float4* __restrict__ hout4, int N) {
    int t = threadIdx.x;
    int d = blockIdx.x * 4 + (t >> 6);
    if (d >= N) return;
    int lane = t & 63;
    int hsel = lane >> 4;
    int row0 = rowptr[d];
    int deg = rowptr[d + 1] - row0;
    float4 acc = make_float4(0.f, 0.f, 0.f, 0.f);
    int j = 0;
    for (; j + 4 <= deg; j += 4) {
        long e0 = row0 + j;
        int s0 = csr_src[e0 + 0];
        int s1 = csr_src[e0 + 1];
        int s2 = csr_src[e0 + 2];
        int s3 = csr_src[e0 + 3];
        float c0 = coeff[(e0 + 0) * 4 + hsel];
        float c1 = coeff[(e0 + 1) * 4 + hsel];
        float c2 = coeff[(e0 + 2) * 4 + hsel];
        float c3 = coeff[(e0 + 3) * 4 + hsel];
        ushort4 u0 = xph4[(long)s0 * 64 + lane];
        ushort4 u1 = xph4[(long)s1 * 64 + lane];
        ushort4 u2 = xph4[(long)s2 * 64 + lane];
        ushort4 u3 = xph4[(long)s3 * 64 + lane];
        acc.x += c0 * bf2f(u0.x); acc.y += c0 * bf2f(u0.y);
        acc.z += c0 * bf2f(u0.z); acc.w += c0 * bf2f(u0.w);
        acc.x += c1 * bf2f(u1.x); acc.y += c1 * bf2f(u1.y);
        acc.z += c1 * bf2f(u1.z); acc.w += c1 * bf2f(u1.w);
        acc.x += c2 * bf2f(u2.x); acc.y += c2 * bf2f(u2.y);
        acc.z += c2 * bf2f(u2.z); acc.w += c2 * bf2f(u2.w);
        acc.x += c3 * bf2f(u3.x); acc.y += c3 * bf2f(u3.y);
        acc.z += c3 * bf2f(u3.z); acc.w += c3 * bf2f(u3.w);
    }
    for (; j < deg; ++j) {
        long e = row0 + j;
        int s = csr_src[e];
        float c = coeff[e * 4 + hsel];
        ushort4 u = xph4[(long)s * 64 + lane];
        acc.x += c * bf2f(u.x); acc.y += c * bf2f(u.y);
        acc.z += c * bf2f(u.z); acc.w += c * bf2f(u.w);
    }
    float4 b = ((const float4*)bias)[lane];
    float4 o;
    float vx = acc.x + b.x; o.x = vx > 0.f ? vx : expm1f(vx);
    float vy = acc.y + b.y; o.y = vy > 0.f ? vy : expm1f(vy);
    float vz = acc.z + b.z; o.z = vz > 0.f ? vz : expm1f(vz);
    float vw = acc.w + b.w; o.w = vw > 0.f ? vw : expm1f(vw);
    hout4[(long)d * 64 + lane] = o;
}

// fp32 fallback (only if ws too small for bf16 copy)
__global__ __launch_bounds__(256) void agg1_gather(const int* __restrict__ rowptr,
        const int* __restrict__ csr_src, const float* __restrict__ coeff,
        const float4* __restrict__ xp4, const float* __restrict__ bias,
        float4* __restrict__ hout4, int N) {
    int t = threadIdx.x;
    int d = blockIdx.x * 4 + (t >> 6);
    if (d >= N) return;
    int lane = t & 63;
    int hsel = lane >> 4;
    int row0 = rowptr[d];
    int deg = rowptr[d + 1] - row0;
    float4 acc = make_float4(0.f, 0.f, 0.f, 0.f);
    for (int j = 0; j < deg; ++j) {
        long e = row0 + j;
        int s = csr_src[e];
        float c = coeff[e * 4 + hsel];
        float4 v = xp4[(long)s * 64 + lane];
        acc.x += c * v.x; acc.y += c * v.y;
        acc.z += c * v.z; acc.w += c * v.w;
    }
    float4 b = ((const float4*)bias)[lane];
    float4 o;
    float vx = acc.x + b.x; o.x = vx > 0.f ? vx : expm1f(vx);
    float vy = acc.y + b.y; o.y = vy > 0.f ? vy : expm1f(vy);
    float vz = acc.z + b.z; o.z = vz > 0.f ? vz : expm1f(vz);
    float vw = acc.w + b.w; o.w = vw > 0.f ? vw : expm1f(vw);
    hout4[(long)d * 64 + lane] = o;
}

// layer 2: 8 nodes/block, 32 lanes per node; fused bias + row softmax; 4x MLP
__global__ __launch_bounds__(256) void agg2_softmax(const int* __restrict__ rowptr,
        const int* __restrict__ csr_src, const float* __restrict__ coeff,
        const float* __restrict__ xp, const float* __restrict__ bias,
        float* __restrict__ out, int N) {
    int t = threadIdx.x;
    int d = blockIdx.x * 8 + (t >> 5);
    if (d >= N) return;
    int c = t & 31;
    int row0 = rowptr[d];
    int deg = rowptr[d + 1] - row0;
    float acc = 0.f;
    int j = 0;
    for (; j + 4 <= deg; j += 4) {
        long e0 = row0 + j;
        int s0 = csr_src[e0 + 0];
        int s1 = csr_src[e0 + 1];
        int s2 = csr_src[e0 + 2];
        int s3 = csr_src[e0 + 3];
        float c0 = coeff[e0 + 0];
        float c1 = coeff[e0 + 1];
        float c2 = coeff[e0 + 2];
        float c3 = coeff[e0 + 3];
        float v0 = xp[(long)s0 * 32 + c];
        float v1 = xp[(long)s1 * 32 + c];
        float v2 = xp[(long)s2 * 32 + c];
        float v3 = xp[(long)s3 * 32 + c];
        acc += c0 * v0;
        acc += c1 * v1;
        acc += c2 * v2;
        acc += c3 * v3;
    }
    for (; j < deg; ++j) {
        long e = row0 + j;
        int s = csr_src[e];
        acc += coeff[e] * xp[(long)s * 32 + c];
    }
    float v = acc + bias[c];
    float mx = v;
    #pragma unroll
    for (int off = 16; off; off >>= 1) mx = fmaxf(mx, __shfl_xor(mx, off, 32));
    float ex = expf(v - mx);
    float sm = ex;
    #pragma unroll
    for (int off = 16; off; off >>= 1) sm += __shfl_xor(sm, off, 32);
    out[(long)d * 32 + c] = ex / sm;
}

// ---------- host ----------
extern "C" void kernel_launch(void* const* d_in, const int* in_sizes, int n_in,
                              void* d_out, int out_size, void* d_ws, size_t ws_size,
                              hipStream_t stream) {
    const float* x   = (const float*)d_in[0];
    const int*   ei  = (const int*)d_in[1];
    const float* W1  = (const float*)d_in[2];
    const float* as1 = (const float*)d_in[3];
    const float* ad1 = (const float*)d_in[4];
    const float* b1  = (const float*)d_in[5];
    const float* W2  = (const float*)d_in[6];
    const float* as2 = (const float*)d_in[7];
    const float* ad2 = (const float*)d_in[8];
    const float* b2  = (const float*)d_in[9];
    float* out = (float*)d_out;

    const int N = in_sizes[0] / 128;     // 50000
    const int E = in_sizes[1] / 2;       // 640000
    const int Etot = E + N;              // + self loops

    // workspace layout (16B-aligned blocks)
    float* ws = (float*)d_ws;
    float* xp1    = ws;                        // N*256 (reused as xp2)
    float* h      = xp1 + (long)N * 256;       // N*256 (reused as coeff2)
    float* a_s1   = h + (long)N * 256;         // N*4
    float* a_d1   = a_s1 + N * 4;              // N*4
    float* a_s2   = a_d1 + N * 4;              // N
    float* a_d2   = a_s2 + N;                  // N
    float* coeff1 = a_d2 + N;                  // Etot*4
    int* deg      = (int*)(coeff1 + (long)Etot * 4); // N
    int* rowptr   = deg + N;                   // N+4 (padded)
    int* cursor   = rowptr + N + 4;            // N
    int* csr_src  = cursor + N;                // Etot
    int* blocksum = csr_src + Etot;            // 256
    int* blockoff = blocksum + 256;            // 256
    unsigned short* xp1h = (unsigned short*)
        ((((uintptr_t)(blockoff + 256)) + 15) & ~(uintptr_t)15);  // N*256 bf16
    size_t need = (size_t)((char*)(xp1h + (size_t)N * 256) - (char*)d_ws);
    bool use_bf16 = (ws_size >= need);
    float* xp2    = xp1;                       // xp1 dead after layer-1 agg
    float* coeff2 = h;                         // h dead after gemm2
    // bf16 GEMM1 inputs alias regions that are only written LATER:
    //   xb  (N*128 bf16 = 12.8MB) lives in h   (h written by agg1, after gemm1)
    //   w1t (256*128 bf16 = 64KB) lives in coeff1 (written by stats_coeff_h4, after gemm1)
    unsigned short* xb  = (unsigned short*)h;
    unsigned short* w1t = (unsigned short*)coeff1;

    hipMemsetAsync(deg, 0, (size_t)N * sizeof(int), stream);

    // ---- CSR build (shared by both layers) ----
    int nbE = (Etot + 255) / 256;
    int nbS = (N + 1023) / 1024;
    count_deg<<<nbE, 256, 0, stream>>>(ei, E, Etot, deg);
    scan_local<<<nbS, 256, 0, stream>>>(deg, rowptr, blocksum, N);
    scan_block_sums<<<1, 256, 0, stream>>>(blocksum, blockoff, nbS);
    scan_add<<<nbS, 256, 0, stream>>>(rowptr, blockoff, cursor, N, Etot);
    scatter_edges<<<nbE, 256, 0, stream>>>(ei, E, Etot, cursor, csr_src);
    sort_rows<<<(N + 3) / 4, 256, 0, stream>>>(rowptr, csr_src, N);

    // ---- layer 1: bf16 MFMA GEMM ----
    {
        long nx = (long)N * 128;
        cast_bf16<<<(int)((nx / 4 + 255) / 256), 256, 0, stream>>>(x, xb, nx);
        transpose_w1<<<128, 256, 0, stream>>>(W1, w1t);
        int waves = (N + 15) / 16;                 // 3125
        int blocks = (waves + 3) / 4;              // 4 waves/block
        gemm1_mfma<<<blocks, 256, 0, stream>>>(xb, w1t, xp1, N);
    }
    att_proj_h4<<<N, 256, 0, stream>>>(xp1, as1, ad1, a_s1, a_d1,
                                       use_bf16 ? xp1h : nullptr, N);
    stats_coeff_h4<<<(N + 3) / 4, 256, 0, stream>>>(rowptr, csr_src, a_s1, a_d1,
                                                    coeff1, N);
    if (use_bf16) {
        agg1_gather_bf16<<<(N + 3) / 4, 256, 0, stream>>>(rowptr, csr_src, coeff1,
                                                  (const ushort4*)xp1h, b1,
                                                  (float4*)h, N);
    } else {
        agg1_gather<<<(N + 3) / 4, 256, 0, stream>>>(rowptr, csr_src, coeff1,
                                                  (const float4*)xp1, b1,
                                                  (float4*)h, N);
    }

    // ---- layer 2 ----
    {
        dim3 g(1, (N + 63) / 64);
        gemm_f32<64, 64, 16><<<g, 256, 0, stream>>>(h, W2, xp2, N, 32, 256);
    }
    att_proj_h1<<<(N + 7) / 8, 256, 0, stream>>>(xp2, as2, ad2, a_s2, a_d2, N);
    stats_coeff_h1<<<(N + 3) / 4, 256, 0, stream>>>(rowptr, csr_src, a_s2, a_d2,
                                                    coeff2, N);
    agg2_softmax<<<(N + 7) / 8, 256, 0, stream>>>(rowptr, csr_src, coeff2,
                                                  xp2, b2, out, N);
}

// Round 10
// 296.700 us; speedup vs baseline: 1.4178x; 1.2827x over previous
//
#include <hip/hip_runtime.h>
#include <math.h>
#include <stdint.h>

#define NEG_SENT -1e30f

typedef __attribute__((ext_vector_type(8))) short bf16x8;
typedef __attribute__((ext_vector_type(4))) float f32x4;

__device__ __forceinline__ unsigned short f2bf(float f) {
    unsigned u = __float_as_uint(f);
    unsigned r = u + 0x7FFFu + ((u >> 16) & 1u);   // round-to-nearest-even
    return (unsigned short)(r >> 16);
}
__device__ __forceinline__ float bf2f(unsigned short h) {
    return __uint_as_float(((unsigned)h) << 16);
}

// ---------- prep ----------
__global__ __launch_bounds__(256) void cast_bf16(const float* __restrict__ in,
        unsigned short* __restrict__ out, long n) {
    long i = ((long)blockIdx.x * 256 + threadIdx.x) * 4;
    if (i + 3 < n) {
        float4 v = *(const float4*)&in[i];
        ushort4 o;
        o.x = f2bf(v.x); o.y = f2bf(v.y); o.z = f2bf(v.z); o.w = f2bf(v.w);
        *(ushort4*)&out[i] = o;
    } else {
        for (long k = i; k < n; ++k) out[k] = f2bf(in[k]);
    }
}

// W1 [128][256] f32 -> w1t [256][128] bf16
__global__ __launch_bounds__(256) void transpose_w1(const float* __restrict__ w,
        unsigned short* __restrict__ wt) {
    int idx = blockIdx.x * 256 + threadIdx.x;   // 32768
    int k = idx & 127;
    int n = idx >> 7;
    wt[idx] = f2bf(w[k * 256 + n]);
}

// W2 [256][32] f32 -> w2t [32][256] bf16
__global__ __launch_bounds__(256) void transpose_w2(const float* __restrict__ w,
        unsigned short* __restrict__ wt) {
    int idx = blockIdx.x * 256 + threadIdx.x;   // 8192
    int k = idx & 255;
    int n = idx >> 8;
    wt[idx] = f2bf(w[k * 32 + n]);
}

// ---------- layer-1 GEMM (bf16 MFMA) + fused attention projections ----------
// xp1h[M,256]bf16 = xb[M,128] @ W1;  a_s/a_d[M,4] = xp1 . att vectors.
// Wave per 16 rows; 16 col-tiles x 4 k-steps 16x16x32.
// C/D: col = lane&15, row = (lane>>4)*4 + reg  [m89-verified]
// head of col nt*16+r is nt>>2 (cols within a tile share a head block of 64).
__global__ __launch_bounds__(256) void gemm1_mfma(
        const unsigned short* __restrict__ xb,
        const unsigned short* __restrict__ w1t,
        const float* __restrict__ att_s, const float* __restrict__ att_d,
        unsigned short* __restrict__ xph,
        float* __restrict__ a_s, float* __restrict__ a_d, int M) {
    int wave = (int)(((long)blockIdx.x * 256 + threadIdx.x) >> 6);
    int lane = threadIdx.x & 63;
    int row0 = wave * 16;
    if (row0 >= M) return;
    int r = lane & 15;
    int g = lane >> 4;
    bf16x8 a[4];
    const unsigned short* arow = xb + (long)(row0 + r) * 128 + g * 8;
    #pragma unroll
    for (int k0 = 0; k0 < 4; ++k0)
        a[k0] = *(const bf16x8*)(arow + k0 * 32);
    float as_v[16], ad_v[16];
    #pragma unroll
    for (int nt = 0; nt < 16; ++nt) {
        as_v[nt] = att_s[nt * 16 + r];
        ad_v[nt] = att_d[nt * 16 + r];
    }
    f32x4 acc[16];
    #pragma unroll
    for (int nt = 0; nt < 16; ++nt) acc[nt] = (f32x4){0.f, 0.f, 0.f, 0.f};
    #pragma unroll
    for (int nt = 0; nt < 16; ++nt) {
        const unsigned short* brow = w1t + (long)(nt * 16 + r) * 128 + g * 8;
        #pragma unroll
        for (int k0 = 0; k0 < 4; ++k0) {
            bf16x8 b = *(const bf16x8*)(brow + k0 * 32);
            acc[nt] = __builtin_amdgcn_mfma_f32_16x16x32_bf16(a[k0], b, acc[nt], 0, 0, 0);
        }
    }
    // epilogue: bf16 store + per-lane projection partials
    float ps[4][4] = {};   // [q][head]
    float pd[4][4] = {};
    #pragma unroll
    for (int nt = 0; nt < 16; ++nt) {
        int hh = nt >> 2;
        #pragma unroll
        for (int q = 0; q < 4; ++q) {
            float v = acc[nt][q];
            xph[(long)(row0 + g * 4 + q) * 256 + nt * 16 + r] = f2bf(v);
            ps[q][hh] += v * as_v[nt];
            pd[q][hh] += v * ad_v[nt];
        }
    }
    // reduce across the 16 lanes of each g-group (xor of bits 0..3 stays in group)
    #pragma unroll
    for (int off = 1; off < 16; off <<= 1) {
        #pragma unroll
        for (int q = 0; q < 4; ++q)
            #pragma unroll
            for (int hh = 0; hh < 4; ++hh) {
                ps[q][hh] += __shfl_xor(ps[q][hh], off);
                pd[q][hh] += __shfl_xor(pd[q][hh], off);
            }
    }
    if (r == 0) {
        #pragma unroll
        for (int q = 0; q < 4; ++q) {
            int row = row0 + g * 4 + q;
            #pragma unroll
            for (int hh = 0; hh < 4; ++hh) {
                a_s[row * 4 + hh] = ps[q][hh];
                a_d[row * 4 + hh] = pd[q][hh];
            }
        }
    }
}

// ---------- layer-2 GEMM (bf16 MFMA) + fused attention projections ----------
// xp2[M,32]f32 = hb[M,256] @ W2; a_s2/a_d2[M] = xp2 . att vectors (32-wide).
__global__ __launch_bounds__(256) void gemm2_mfma(
        const unsigned short* __restrict__ hb,
        const unsigned short* __restrict__ w2t,
        const float* __restrict__ att_s, const float* __restrict__ att_d,
        float* __restrict__ xp2,
        float* __restrict__ a_s, float* __restrict__ a_d, int M) {
    int wave = (int)(((long)blockIdx.x * 256 + threadIdx.x) >> 6);
    int lane = threadIdx.x & 63;
    int row0 = wave * 16;
    if (row0 >= M) return;
    int r = lane & 15;
    int g = lane >> 4;
    bf16x8 a[8];
    const unsigned short* arow = hb + (long)(row0 + r) * 256 + g * 8;
    #pragma unroll
    for (int k0 = 0; k0 < 8; ++k0)
        a[k0] = *(const bf16x8*)(arow + k0 * 32);
    float as_v[2], ad_v[2];
    #pragma unroll
    for (int nt = 0; nt < 2; ++nt) {
        as_v[nt] = att_s[nt * 16 + r];
        ad_v[nt] = att_d[nt * 16 + r];
    }
    f32x4 acc[2];
    acc[0] = (f32x4){0.f, 0.f, 0.f, 0.f};
    acc[1] = (f32x4){0.f, 0.f, 0.f, 0.f};
    #pragma unroll
    for (int nt = 0; nt < 2; ++nt) {
        const unsigned short* brow = w2t + (long)(nt * 16 + r) * 256 + g * 8;
        #pragma unroll
        for (int k0 = 0; k0 < 8; ++k0) {
            bf16x8 b = *(const bf16x8*)(brow + k0 * 32);
            acc[nt] = __builtin_amdgcn_mfma_f32_16x16x32_bf16(a[k0], b, acc[nt], 0, 0, 0);
        }
    }
    float ps[4] = {}, pd[4] = {};
    #pragma unroll
    for (int nt = 0; nt < 2; ++nt) {
        #pragma unroll
        for (int q = 0; q < 4; ++q) {
            float v = acc[nt][q];
            xp2[(long)(row0 + g * 4 + q) * 32 + nt * 16 + r] = v;
            ps[q] += v * as_v[nt];
            pd[q] += v * ad_v[nt];
        }
    }
    #pragma unroll
    for (int off = 1; off < 16; off <<= 1) {
        #pragma unroll
        for (int q = 0; q < 4; ++q) {
            ps[q] += __shfl_xor(ps[q], off);
            pd[q] += __shfl_xor(pd[q], off);
        }
    }
    if (r == 0) {
        #pragma unroll
        for (int q = 0; q < 4; ++q) {
            a_s[row0 + g * 4 + q] = ps[q];
            a_d[row0 + g * 4 + q] = pd[q];
        }
    }
}

// ---------- CSR build ----------
__global__ __launch_bounds__(256) void count_deg(const int* __restrict__ ei,
        int E, int Etot, int* __restrict__ deg) {
    int e = blockIdx.x * 256 + threadIdx.x;
    if (e >= Etot) return;
    int d = (e < E) ? ei[E + e] : e - E;
    atomicAdd(&deg[d], 1);
}

__global__ __launch_bounds__(256) void scan_local(const int* __restrict__ deg,
        int* __restrict__ rowptr, int* __restrict__ blocksum, int N) {
    __shared__ int part[256];
    int b = blockIdx.x, t = threadIdx.x;
    int base = b * 1024 + t * 4;
    int4 v = make_int4(0, 0, 0, 0);
    if (base + 3 < N) {
        v = *(const int4*)(deg + base);
    } else {
        if (base + 0 < N) v.x = deg[base + 0];
        if (base + 1 < N) v.y = deg[base + 1];
        if (base + 2 < N) v.z = deg[base + 2];
        if (base + 3 < N) v.w = deg[base + 3];
    }
    part[t] = v.x + v.y + v.z + v.w;
    __syncthreads();
    #pragma unroll
    for (int off = 1; off < 256; off <<= 1) {
        int val = (t >= off) ? part[t - off] : 0;
        __syncthreads();
        part[t] += val;
        __syncthreads();
    }
    if (t == 255) blocksum[b] = part[255];
    int r0 = (t > 0) ? part[t - 1] : 0;
    int r1 = r0 + v.x;
    int r2 = r1 + v.y;
    int r3 = r2 + v.z;
    if (base + 3 < N) {
        *(int4*)(rowptr + base) = make_int4(r0, r1, r2, r3);
    } else {
        if (base + 0 < N) rowptr[base + 0] = r0;
        if (base + 1 < N) rowptr[base + 1] = r1;
        if (base + 2 < N) rowptr[base + 2] = r2;
        if (base + 3 < N) rowptr[base + 3] = r3;
    }
}

__global__ __launch_bounds__(256) void scan_block_sums(const int* __restrict__ blocksum,
        int* __restrict__ blockoff, int nb) {
    __shared__ int part[256];
    int t = threadIdx.x;
    part[t] = (t < nb) ? blocksum[t] : 0;
    __syncthreads();
    #pragma unroll
    for (int off = 1; off < 256; off <<= 1) {
        int val = (t >= off) ? part[t - off] : 0;
        __syncthreads();
        part[t] += val;
        __syncthreads();
    }
    if (t < nb) blockoff[t] = (t > 0) ? part[t - 1] : 0;
}

__global__ __launch_bounds__(256) void scan_add(int* __restrict__ rowptr,
        const int* __restrict__ blockoff, int* __restrict__ cursor,
        int N, int Etot) {
    int b = blockIdx.x, t = threadIdx.x;
    int base = b * 1024 + t * 4;
    int off = blockoff[b];
    if (base + 3 < N) {
        int4 v = *(const int4*)(rowptr + base);
        v.x += off; v.y += off; v.z += off; v.w += off;
        *(int4*)(rowptr + base) = v;
        *(int4*)(cursor + base) = v;
    } else {
        for (int i = 0; i < 4; ++i) {
            if (base + i < N) {
                int v = rowptr[base + i] + off;
                rowptr[base + i] = v;
                cursor[base + i] = v;
            }
        }
    }
    if (b == 0 && t == 0) rowptr[N] = Etot;
}

__global__ __launch_bounds__(256) void scatter_edges(const int* __restrict__ ei,
        int E, int Etot, int* __restrict__ cursor, int* __restrict__ csr_src) {
    int e = blockIdx.x * 256 + threadIdx.x;
    if (e >= Etot) return;
    int s, d;
    if (e < E) { s = ei[e]; d = ei[E + e]; } else { s = e - E; d = s; }
    int pos = atomicAdd(&cursor[d], 1);
    csr_src[pos] = s;
}

// ---------- canonicalize CSR rows (determinism across calls/replays) ----------
__global__ __launch_bounds__(256) void sort_rows(const int* __restrict__ rowptr,
        int* __restrict__ csr_src, int N) {
    __shared__ int buf[4][256];
    __shared__ int mxw[4];
    int t = threadIdx.x;
    int w = t >> 6;
    int lane = t & 63;
    int d = blockIdx.x * 4 + w;
    int row0 = 0, deg = 0;
    if (d < N) { row0 = rowptr[d]; deg = rowptr[d + 1] - row0; }
    int capped = (deg <= 256) ? deg : 0;
    for (int j = lane; j < capped; j += 64) buf[w][j] = csr_src[row0 + j];
    int m = capped;
    #pragma unroll
    for (int off = 32; off; off >>= 1) m = max(m, __shfl_xor(m, off));
    if (lane == 0) mxw[w] = m;
    __syncthreads();
    int itmax = max(max(mxw[0], mxw[1]), max(mxw[2], mxw[3]));
    for (int it = 0; it < itmax; ++it) {
        int start = it & 1;
        #pragma unroll
        for (int rep = 0; rep < 2; ++rep) {
            int k = start + 2 * lane + rep * 128;
            if (k + 1 < capped) {
                int a = buf[w][k], b = buf[w][k + 1];
                if (a > b) { buf[w][k] = b; buf[w][k + 1] = a; }
            }
        }
        __syncthreads();
    }
    for (int j = lane; j < capped; j += 64) csr_src[row0 + j] = buf[w][j];
    if (deg > 256 && lane == 0) {
        for (int i = 1; i < deg; ++i) {
            int key = csr_src[row0 + i];
            int k = i - 1;
            while (k >= 0 && csr_src[row0 + k] > key) {
                csr_src[row0 + k + 1] = csr_src[row0 + k];
                --k;
            }
            csr_src[row0 + k + 1] = key;
        }
    }
}

// ---------- softmax stats + coefficient precompute ----------
__device__ __forceinline__ void merge_ms(float& m, float& s, float m2, float s2) {
    float mn = fmaxf(m, m2);
    s = s * expf(m - mn) + s2 * expf(m2 - mn);
    m = mn;
}

__global__ __launch_bounds__(256) void stats_coeff_h4(const int* __restrict__ rowptr,
        const int* __restrict__ csr_src, const float* __restrict__ a_s,
        const float* __restrict__ a_d, float* __restrict__ coeff, int N) {
    int t = threadIdx.x;
    int d = blockIdx.x * 4 + (t >> 6);
    if (d >= N) return;
    int lane = t & 63;
    int h = lane & 3;
    int j0 = lane >> 2;
    int row0 = rowptr[d];
    int deg = rowptr[d + 1] - row0;
    float ad = a_d[d * 4 + h];
    float m = NEG_SENT, s = 0.f;
    for (int j = j0; j < deg; j += 16) {
        int sn = csr_src[row0 + j];
        float l = a_s[sn * 4 + h] + ad;
        l = l > 0.f ? l : 0.2f * l;
        float mn = fmaxf(m, l);
        s = s * expf(m - mn) + expf(l - mn);
        m = mn;
    }
    #pragma unroll
    for (int off = 4; off <= 32; off <<= 1) {
        float m2 = __shfl_xor(m, off);
        float s2 = __shfl_xor(s, off);
        merge_ms(m, s, m2, s2);
    }
    float inv = 1.f / (s + 1e-16f);
    for (int j = j0; j < deg; j += 16) {
        int sn = csr_src[row0 + j];
        float l = a_s[sn * 4 + h] + ad;
        l = l > 0.f ? l : 0.2f * l;
        coeff[(long)(row0 + j) * 4 + h] = expf(l - m) * inv;
    }
}

__global__ __launch_bounds__(256) void stats_coeff_h1(const int* __restrict__ rowptr,
        const int* __restrict__ csr_src, const float* __restrict__ a_s,
        const float* __restrict__ a_d, float* __restrict__ coeff, int N) {
    int t = threadIdx.x;
    int d = blockIdx.x * 4 + (t >> 6);
    if (d >= N) return;
    int lane = t & 63;
    int row0 = rowptr[d];
    int deg = rowptr[d + 1] - row0;
    float ad = a_d[d];
    float m = NEG_SENT, s = 0.f;
    for (int j = lane; j < deg; j += 64) {
        int sn = csr_src[row0 + j];
        float l = a_s[sn] + ad;
        l = l > 0.f ? l : 0.2f * l;
        float mn = fmaxf(m, l);
        s = s * expf(m - mn) + expf(l - mn);
        m = mn;
    }
    #pragma unroll
    for (int off = 1; off <= 32; off <<= 1) {
        float m2 = __shfl_xor(m, off);
        float s2 = __shfl_xor(s, off);
        merge_ms(m, s, m2, s2);
    }
    float inv = 1.f / (s + 1e-16f);
    for (int j = lane; j < deg; j += 64) {
        int sn = csr_src[row0 + j];
        float l = a_s[sn] + ad;
        l = l > 0.f ? l : 0.2f * l;
        coeff[row0 + j] = expf(l - m) * inv;
    }
}

// ---------- layer-1 aggregation (bf16 gather, bf16 out) ----------
__global__ __launch_bounds__(256) void agg1_gather_bf16(const int* __restrict__ rowptr,
        const int* __restrict__ csr_src, const float* __restrict__ coeff,
        const ushort4* __restrict__ xph4, const float* __restrict__ bias,
        ushort4* __restrict__ hb4, int N) {
    int t = threadIdx.x;
    int d = blockIdx.x * 4 + (t >> 6);
    if (d >= N) return;
    int lane = t & 63;
    int hsel = lane >> 4;
    int row0 = rowptr[d];
    int deg = rowptr[d + 1] - row0;
    float4 acc = make_float4(0.f, 0.f, 0.f, 0.f);
    int j = 0;
    for (; j + 4 <= deg; j += 4) {
        long e0 = row0 + j;
        int s0 = csr_src[e0 + 0];
        int s1 = csr_src[e0 + 1];
        int s2 = csr_src[e0 + 2];
        int s3 = csr_src[e0 + 3];
        float c0 = coeff[(e0 + 0) * 4 + hsel];
        float c1 = coeff[(e0 + 1) * 4 + hsel];
        float c2 = coeff[(e0 + 2) * 4 + hsel];
        float c3 = coeff[(e0 + 3) * 4 + hsel];
        ushort4 u0 = xph4[(long)s0 * 64 + lane];
        ushort4 u1 = xph4[(long)s1 * 64 + lane];
        ushort4 u2 = xph4[(long)s2 * 64 + lane];
        ushort4 u3 = xph4[(long)s3 * 64 + lane];
        acc.x += c0 * bf2f(u0.x); acc.y += c0 * bf2f(u0.y);
        acc.z += c0 * bf2f(u0.z); acc.w += c0 * bf2f(u0.w);
        acc.x += c1 * bf2f(u1.x); acc.y += c1 * bf2f(u1.y);
        acc.z += c1 * bf2f(u1.z); acc.w += c1 * bf2f(u1.w);
        acc.x += c2 * bf2f(u2.x); acc.y += c2 * bf2f(u2.y);
        acc.z += c2 * bf2f(u2.z); acc.w += c2 * bf2f(u2.w);
        acc.x += c3 * bf2f(u3.x); acc.y += c3 * bf2f(u3.y);
        acc.z += c3 * bf2f(u3.z); acc.w += c3 * bf2f(u3.w);
    }
    for (; j < deg; ++j) {
        long e = row0 + j;
        int s = csr_src[e];
        float c = coeff[e * 4 + hsel];
        ushort4 u = xph4[(long)s * 64 + lane];
        acc.x += c * bf2f(u.x); acc.y += c * bf2f(u.y);
        acc.z += c * bf2f(u.z); acc.w += c * bf2f(u.w);
    }
    float4 b = ((const float4*)bias)[lane];
    float vx = acc.x + b.x; vx = vx > 0.f ? vx : expm1f(vx);
    float vy = acc.y + b.y; vy = vy > 0.f ? vy : expm1f(vy);
    float vz = acc.z + b.z; vz = vz > 0.f ? vz : expm1f(vz);
    float vw = acc.w + b.w; vw = vw > 0.f ? vw : expm1f(vw);
    ushort4 o;
    o.x = f2bf(vx); o.y = f2bf(vy); o.z = f2bf(vz); o.w = f2bf(vw);
    hb4[(long)d * 64 + lane] = o;
}

// ---------- layer-2 aggregation + row softmax ----------
__global__ __launch_bounds__(256) void agg2_softmax(const int* __restrict__ rowptr,
        const int* __restrict__ csr_src, const float* __restrict__ coeff,
        const float* __restrict__ xp, const float* __restrict__ bias,
        float* __restrict__ out, int N) {
    int t = threadIdx.x;
    int d = blockIdx.x * 8 + (t >> 5);
    if (d >= N) return;
    int c = t & 31;
    int row0 = rowptr[d];
    int deg = rowptr[d + 1] - row0;
    float acc = 0.f;
    int j = 0;
    for (; j + 4 <= deg; j += 4) {
        long e0 = row0 + j;
        int s0 = csr_src[e0 + 0];
        int s1 = csr_src[e0 + 1];
        int s2 = csr_src[e0 + 2];
        int s3 = csr_src[e0 + 3];
        float c0 = coeff[e0 + 0];
        float c1 = coeff[e0 + 1];
        float c2 = coeff[e0 + 2];
        float c3 = coeff[e0 + 3];
        float v0 = xp[(long)s0 * 32 + c];
        float v1 = xp[(long)s1 * 32 + c];
        float v2 = xp[(long)s2 * 32 + c];
        float v3 = xp[(long)s3 * 32 + c];
        acc += c0 * v0;
        acc += c1 * v1;
        acc += c2 * v2;
        acc += c3 * v3;
    }
    for (; j < deg; ++j) {
        long e = row0 + j;
        int s = csr_src[e];
        acc += coeff[e] * xp[(long)s * 32 + c];
    }
    float v = acc + bias[c];
    float mx = v;
    #pragma unroll
    for (int off = 16; off; off >>= 1) mx = fmaxf(mx, __shfl_xor(mx, off, 32));
    float ex = expf(v - mx);
    float sm = ex;
    #pragma unroll
    for (int off = 16; off; off >>= 1) sm += __shfl_xor(sm, off, 32);
    out[(long)d * 32 + c] = ex / sm;
}

// ---------- host ----------
extern "C" void kernel_launch(void* const* d_in, const int* in_sizes, int n_in,
                              void* d_out, int out_size, void* d_ws, size_t ws_size,
                              hipStream_t stream) {
    const float* x   = (const float*)d_in[0];
    const int*   ei  = (const int*)d_in[1];
    const float* W1  = (const float*)d_in[2];
    const float* as1 = (const float*)d_in[3];
    const float* ad1 = (const float*)d_in[4];
    const float* b1  = (const float*)d_in[5];
    const float* W2  = (const float*)d_in[6];
    const float* as2 = (const float*)d_in[7];
    const float* ad2 = (const float*)d_in[8];
    const float* b2  = (const float*)d_in[9];
    float* out = (float*)d_out;

    const int N = in_sizes[0] / 128;     // 50000
    const int E = in_sizes[1] / 2;       // 640000
    const int Etot = E + N;              // + self loops

    // workspace layout (all 16B-aligned; ~90 MB total)
    unsigned short* xp1h = (unsigned short*)d_ws;        // N*256 bf16
    unsigned short* hb   = xp1h + (long)N * 256;         // N*256 bf16
    unsigned short* xb   = hb + (long)N * 256;           // N*128 bf16
    unsigned short* w1t  = xb + (long)N * 128;           // 32768 bf16
    unsigned short* w2t  = w1t + 32768;                  // 8192 bf16
    float* a_s1   = (float*)(w2t + 8192);                // N*4
    float* a_d1   = a_s1 + (long)N * 4;                  // N*4
    float* a_s2   = a_d1 + (long)N * 4;                  // N
    float* a_d2   = a_s2 + N;                            // N
    float* coeff1 = a_d2 + N;                            // Etot*4
    float* coeff2 = coeff1 + (long)Etot * 4;             // Etot
    float* xp2    = coeff2 + Etot;                       // N*32
    int* deg      = (int*)(xp2 + (long)N * 32);          // N
    int* rowptr   = deg + N;                             // N+4 (padded)
    int* cursor   = rowptr + N + 4;                      // N
    int* csr_src  = cursor + N;                          // Etot
    int* blocksum = csr_src + Etot;                      // 256
    int* blockoff = blocksum + 256;                      // 256

    hipMemsetAsync(deg, 0, (size_t)N * sizeof(int), stream);

    // ---- CSR build (shared by both layers) ----
    int nbE = (Etot + 255) / 256;
    int nbS = (N + 1023) / 1024;
    count_deg<<<nbE, 256, 0, stream>>>(ei, E, Etot, deg);
    scan_local<<<nbS, 256, 0, stream>>>(deg, rowptr, blocksum, N);
    scan_block_sums<<<1, 256, 0, stream>>>(blocksum, blockoff, nbS);
    scan_add<<<nbS, 256, 0, stream>>>(rowptr, blockoff, cursor, N, Etot);
    scatter_edges<<<nbE, 256, 0, stream>>>(ei, E, Etot, cursor, csr_src);
    sort_rows<<<(N + 3) / 4, 256, 0, stream>>>(rowptr, csr_src, N);

    int gemmBlocks = (((N + 15) / 16) + 3) / 4;   // 4 waves/block

    // ---- layer 1 ----
    {
        long nx = (long)N * 128;
        cast_bf16<<<(int)((nx / 4 + 255) / 256), 256, 0, stream>>>(x, xb, nx);
        transpose_w1<<<128, 256, 0, stream>>>(W1, w1t);
        gemm1_mfma<<<gemmBlocks, 256, 0, stream>>>(xb, w1t, as1, ad1,
                                                   xp1h, a_s1, a_d1, N);
    }
    stats_coeff_h4<<<(N + 3) / 4, 256, 0, stream>>>(rowptr, csr_src, a_s1, a_d1,
                                                    coeff1, N);
    agg1_gather_bf16<<<(N + 3) / 4, 256, 0, stream>>>(rowptr, csr_src, coeff1,
                                              (const ushort4*)xp1h, b1,
                                              (ushort4*)hb, N);

    // ---- layer 2 ----
    {
        transpose_w2<<<32, 256, 0, stream>>>(W2, w2t);
        gemm2_mfma<<<gemmBlocks, 256, 0, stream>>>(hb, w2t, as2, ad2,
                                                   xp2, a_s2, a_d2, N);
    }
    stats_coeff_h1<<<(N + 3) / 4, 256, 0, stream>>>(rowptr, csr_src, a_s2, a_d2,
                                                    coeff2, N);
    agg2_softmax<<<(N + 7) / 8, 256, 0, stream>>>(rowptr, csr_src, coeff2,
                                                  xp2, b2, out, N);
}